// Round 1
// baseline (1415.002 us; speedup 1.0000x reference)
//
#include <hip/hip_runtime.h>

// ---------------------------------------------------------------------------
// AttentionLayer: B=16 S=12 N=400 D=512 H=8 HD=64
// outputs (flat concat, fp32): out[16,12,400,512] | scores_hb[128,12,400,400]
//                              | v_hb[128,12,400,64]
// ---------------------------------------------------------------------------

typedef float fvec4 __attribute__((ext_vector_type(4)));
typedef float f32x4 __attribute__((ext_vector_type(4)));
typedef unsigned short usvec4 __attribute__((ext_vector_type(4)));
typedef unsigned short usvec8 __attribute__((ext_vector_type(8)));
typedef short v8s __attribute__((ext_vector_type(8)));

#define DEV __device__ __forceinline__

DEV unsigned short f2bf(float f) {
  unsigned int u = __builtin_bit_cast(unsigned int, f);
  u += 0x7FFFu + ((u >> 16) & 1u);     // RNE round to bf16
  return (unsigned short)(u >> 16);
}

DEV f32x4 mfma16(v8s a, v8s b, f32x4 c) {
  return __builtin_amdgcn_mfma_f32_16x16x32_bf16(a, b, c, 0, 0, 0);
}

// ---------------------------------------------------------------------------
// GEMM: C[m][n] = sum_k A[m][k] * W[n][k] + bias[n]
// A: 76800 x 512 (fp32 if AMODE==0, bf16 bits if AMODE==1), W: 512x512 fp32.
// OMODE 0: bf16 -> Out[m*512+n] (ws)
// OMODE 1: fp32 -> v_hb scatter ((h*192+bs)*400+node)*64+hd
// OMODE 2: fp32 -> Out[m*512+n] (d_out)
// tile 128x128x32, 4 waves, each wave 64x64 (4x4 frags of 16x16x32)
// ---------------------------------------------------------------------------
template <int AMODE, int OMODE>
__global__ __launch_bounds__(256) void gemm_k(const void* __restrict__ Av,
                                              const float* __restrict__ W,
                                              const float* __restrict__ bias,
                                              void* __restrict__ Outv) {
  __shared__ unsigned short sA[128][56];  // pitch 112B: 16B-aligned, 2-way banks
  __shared__ unsigned short sB[128][56];
  const int t = threadIdx.x;
  const int lane = t & 63, wid = t >> 6;
  const int wm = wid >> 1, wn = wid & 1;
  const int lr = lane & 15, lg = lane >> 4;
  const long m0 = (long)blockIdx.x * 128;
  const int n0 = blockIdx.y * 128;

  f32x4 acc[4][4] = {};

  for (int k0 = 0; k0 < 512; k0 += 32) {
    __syncthreads();
    if (AMODE == 0) {
      const float* A = (const float*)Av;
#pragma unroll
      for (int p = 0; p < 4; p++) {
        int ci = t + p * 256;
        int row = ci >> 3, c = (ci & 7) * 4;
        fvec4 v = *reinterpret_cast<const fvec4*>(A + (m0 + row) * 512 + k0 + c);
        usvec4 pk;
        pk[0] = f2bf(v[0]); pk[1] = f2bf(v[1]); pk[2] = f2bf(v[2]); pk[3] = f2bf(v[3]);
        *reinterpret_cast<usvec4*>(&sA[row][c]) = pk;
      }
    } else {
      const unsigned short* A = (const unsigned short*)Av;
#pragma unroll
      for (int p = 0; p < 2; p++) {
        int ci = t + p * 256;
        int row = ci >> 2, c = (ci & 3) * 8;
        usvec8 v = *reinterpret_cast<const usvec8*>(A + (m0 + row) * 512 + k0 + c);
        *reinterpret_cast<usvec8*>(&sA[row][c]) = v;
      }
    }
    {
#pragma unroll
      for (int p = 0; p < 4; p++) {
        int ci = t + p * 256;
        int row = ci >> 3, c = (ci & 7) * 4;
        fvec4 v = *reinterpret_cast<const fvec4*>(W + (long)(n0 + row) * 512 + k0 + c);
        usvec4 pk;
        pk[0] = f2bf(v[0]); pk[1] = f2bf(v[1]); pk[2] = f2bf(v[2]); pk[3] = f2bf(v[3]);
        *reinterpret_cast<usvec4*>(&sB[row][c]) = pk;
      }
    }
    __syncthreads();

    v8s af[4], bf[4];
#pragma unroll
    for (int i = 0; i < 4; i++)
      af[i] = *reinterpret_cast<const v8s*>(&sA[wm * 64 + i * 16 + lr][lg * 8]);
#pragma unroll
    for (int j = 0; j < 4; j++)
      bf[j] = *reinterpret_cast<const v8s*>(&sB[wn * 64 + j * 16 + lr][lg * 8]);
#pragma unroll
    for (int i = 0; i < 4; i++)
#pragma unroll
      for (int j = 0; j < 4; j++) acc[i][j] = mfma16(af[i], bf[j], acc[i][j]);
  }

#pragma unroll
  for (int i = 0; i < 4; i++) {
#pragma unroll
    for (int j = 0; j < 4; j++) {
      const int gn = n0 + wn * 64 + j * 16 + lr;
      const float bv = bias[gn];
#pragma unroll
      for (int r = 0; r < 4; r++) {
        const long gm = m0 + wm * 64 + i * 16 + lg * 4 + r;
        const float val = acc[i][j][r] + bv;
        if (OMODE == 0) {
          ((unsigned short*)Outv)[gm * 512 + gn] = f2bf(val);
        } else if (OMODE == 1) {
          const int bs_lin = (int)(gm / 400);
          const int node = (int)(gm - (long)bs_lin * 400);
          const int h = gn >> 6, hd = gn & 63;
          ((float*)Outv)[(((long)(h * 192 + bs_lin) * 400 + node) << 6) + hd] = val;
        } else {
          ((float*)Outv)[gm * 512 + gn] = val;
        }
      }
    }
  }
}

// ---------------------------------------------------------------------------
// scores[(h*192+bs)*160000 + q*400 + k] = (1/8) * sum_d q[bs,q,h,d]*k[bs,k,h,d]
// grid (4,4,1536), tile 128x128, K=64
// ---------------------------------------------------------------------------
__global__ __launch_bounds__(256) void scores_k(const unsigned short* __restrict__ qm,
                                                const unsigned short* __restrict__ km,
                                                float* __restrict__ sc) {
  __shared__ unsigned short sQ[128][88];  // pitch 176B
  __shared__ unsigned short sK[128][88];
  const int t = threadIdx.x;
  const int lane = t & 63, wid = t >> 6;
  const int wm = wid >> 1, wn = wid & 1;
  const int lr = lane & 15, lg = lane >> 4;
  const int g = blockIdx.z, bs = g >> 3, h = g & 7;
  const int q0 = blockIdx.x * 128, kt0 = blockIdx.y * 128;
  const long base = (long)bs * 400 * 512 + h * 64;

#pragma unroll
  for (int p = 0; p < 4; p++) {
    int ci = t + p * 256;
    int row = ci >> 3, c = (ci & 7) * 8;
    int nq = q0 + row; if (nq > 399) nq = 399;
    *reinterpret_cast<usvec8*>(&sQ[row][c]) =
        *reinterpret_cast<const usvec8*>(qm + base + (long)nq * 512 + c);
    int nk = kt0 + row; if (nk > 399) nk = 399;
    *reinterpret_cast<usvec8*>(&sK[row][c]) =
        *reinterpret_cast<const usvec8*>(km + base + (long)nk * 512 + c);
  }
  __syncthreads();

  f32x4 acc[4][4] = {};
#pragma unroll
  for (int ks = 0; ks < 2; ks++) {
    v8s af[4], bf[4];
#pragma unroll
    for (int i = 0; i < 4; i++)
      af[i] = *reinterpret_cast<const v8s*>(&sQ[wm * 64 + i * 16 + lr][ks * 32 + lg * 8]);
#pragma unroll
    for (int j = 0; j < 4; j++)
      bf[j] = *reinterpret_cast<const v8s*>(&sK[wn * 64 + j * 16 + lr][ks * 32 + lg * 8]);
#pragma unroll
    for (int i = 0; i < 4; i++)
#pragma unroll
      for (int j = 0; j < 4; j++) acc[i][j] = mfma16(af[i], bf[j], acc[i][j]);
  }

  const long sbase = (long)(h * 192 + bs) * 160000;
#pragma unroll
  for (int i = 0; i < 4; i++) {
#pragma unroll
    for (int j = 0; j < 4; j++) {
      const int kk = kt0 + wn * 64 + j * 16 + lr;
#pragma unroll
      for (int r = 0; r < 4; r++) {
        const int qq = q0 + wm * 64 + i * 16 + lg * 4 + r;
        if (qq < 400 && kk < 400)
          sc[sbase + (long)qq * 400 + kk] = acc[i][j][r] * 0.125f;
      }
    }
  }
}

// ---------------------------------------------------------------------------
// per-row softmax stats: max and 1/sum(exp(x-max)); one wave per row of 400
// ---------------------------------------------------------------------------
__global__ __launch_bounds__(256) void stats_k(const float* __restrict__ sc,
                                               float* __restrict__ smax,
                                               float* __restrict__ sinv) {
  const int t = threadIdx.x, lane = t & 63, w = t >> 6;
  const long row = (long)blockIdx.x * 4 + w;
  const float* p = sc + row * 400;
  float vals[7];
  float m = -3.0e38f;
#pragma unroll
  for (int i = 0; i < 7; i++) {
    int idx = lane + i * 64;
    vals[i] = (idx < 400) ? p[idx] : -3.0e38f;
    m = fmaxf(m, vals[i]);
  }
#pragma unroll
  for (int off = 32; off > 0; off >>= 1) m = fmaxf(m, __shfl_xor(m, off));
  float s = 0.f;
#pragma unroll
  for (int i = 0; i < 7; i++) {
    int idx = lane + i * 64;
    if (idx < 400) s += __expf(vals[i] - m);
  }
#pragma unroll
  for (int off = 32; off > 0; off >>= 1) s += __shfl_xor(s, off);
  if (lane == 0) {
    smax[row] = m;
    sinv[row] = 1.0f / s;
  }
}

// ---------------------------------------------------------------------------
// ctx[bs*400+q][h*64+hd] = (1/sum_q) * sum_k exp(sc[q][k]-max_q) * v_hb[k][hd]
// grid (7, 1536); tile 64(q) x 64(hd), K-loop over 400 in steps of 64
// ---------------------------------------------------------------------------
__global__ __launch_bounds__(256) void pv_k(const float* __restrict__ sc,
                                            const float* __restrict__ vhb,
                                            const float* __restrict__ smax,
                                            const float* __restrict__ sinv,
                                            unsigned short* __restrict__ ctx) {
  __shared__ unsigned short sP[64][88];
  __shared__ unsigned short sVT[64][88];  // transposed: [hd][kk]
  __shared__ float lmax[64], linv[64];
  const int t = threadIdx.x;
  const int lane = t & 63, wid = t >> 6;
  const int wm = wid >> 1, wn = wid & 1;
  const int lr = lane & 15, lg = lane >> 4;
  const int g = blockIdx.y, bs = g >> 3, h = g & 7;
  const int q0 = blockIdx.x * 64;
  const long srow0 = (long)(h * 192 + bs) * 400;

  if (t < 64) {
    int qq = q0 + t;
    if (qq > 399) qq = 399;
    lmax[t] = smax[srow0 + qq];
    linv[t] = sinv[srow0 + qq];
  }

  f32x4 acc[2][2] = {};
  const long scb = srow0 * 400;
  const long vb = srow0 * 64;

  for (int kt = 0; kt < 400; kt += 64) {
    __syncthreads();
#pragma unroll
    for (int p = 0; p < 4; p++) {
      int ci = t + p * 256;
      int row = ci >> 4, c = (ci & 15) * 4;
      // P tile (exp applied, bf16)
      int qq = q0 + row, kk = kt + c;
      usvec4 pk;
      pk[0] = 0; pk[1] = 0; pk[2] = 0; pk[3] = 0;
      if (qq < 400 && kk < 400) {
        fvec4 v = *reinterpret_cast<const fvec4*>(sc + scb + (long)qq * 400 + kk);
        float mrow = lmax[row];
        pk[0] = f2bf(__expf(v[0] - mrow));
        pk[1] = f2bf(__expf(v[1] - mrow));
        pk[2] = f2bf(__expf(v[2] - mrow));
        pk[3] = f2bf(__expf(v[3] - mrow));
      }
      *reinterpret_cast<usvec4*>(&sP[row][c]) = pk;
      // V tile, transposed into sVT[hd][kk]
      int kv = kt + row;
      if (kv < 400) {
        fvec4 v = *reinterpret_cast<const fvec4*>(vhb + vb + (long)kv * 64 + c);
        sVT[c + 0][row] = f2bf(v[0]);
        sVT[c + 1][row] = f2bf(v[1]);
        sVT[c + 2][row] = f2bf(v[2]);
        sVT[c + 3][row] = f2bf(v[3]);
      } else {
        sVT[c + 0][row] = 0; sVT[c + 1][row] = 0;
        sVT[c + 2][row] = 0; sVT[c + 3][row] = 0;
      }
    }
    __syncthreads();
#pragma unroll
    for (int ks = 0; ks < 2; ks++) {
      v8s af[2], bf[2];
#pragma unroll
      for (int i = 0; i < 2; i++)
        af[i] = *reinterpret_cast<const v8s*>(&sP[wm * 32 + i * 16 + lr][ks * 32 + lg * 8]);
#pragma unroll
      for (int j = 0; j < 2; j++)
        bf[j] = *reinterpret_cast<const v8s*>(&sVT[wn * 32 + j * 16 + lr][ks * 32 + lg * 8]);
#pragma unroll
      for (int i = 0; i < 2; i++)
#pragma unroll
        for (int j = 0; j < 2; j++) acc[i][j] = mfma16(af[i], bf[j], acc[i][j]);
    }
  }

#pragma unroll
  for (int i = 0; i < 2; i++) {
#pragma unroll
    for (int j = 0; j < 2; j++) {
#pragma unroll
      for (int r = 0; r < 4; r++) {
        const int ql = wm * 32 + i * 16 + lg * 4 + r;
        const int qq = q0 + ql;
        if (qq < 400) {
          const int hd = wn * 32 + j * 16 + lr;
          const float val = acc[i][j][r] * linv[ql];
          ctx[(long)(bs * 400 + qq) * 512 + h * 64 + hd] = f2bf(val);
        }
      }
    }
  }
}

// ---------------------------------------------------------------------------

extern "C" void kernel_launch(void* const* d_in, const int* in_sizes, int n_in,
                              void* d_out, int out_size, void* d_ws, size_t ws_size,
                              hipStream_t stream) {
  (void)in_sizes; (void)n_in; (void)out_size; (void)ws_size;

  const float* query = (const float*)d_in[0];
  const float* key   = (const float*)d_in[1];
  const float* value = (const float*)d_in[2];
  const float* Wq = (const float*)d_in[3];
  const float* bq = (const float*)d_in[4];
  const float* Wk = (const float*)d_in[5];
  const float* bk = (const float*)d_in[6];
  const float* Wv = (const float*)d_in[7];
  const float* bv = (const float*)d_in[8];
  const float* Wo = (const float*)d_in[9];
  const float* bo = (const float*)d_in[10];

  float* out = (float*)d_out;                 // 39,321,600 f32
  float* sc  = out + 39321600ULL;             // 245,760,000 f32
  float* vhb = sc + 245760000ULL;             // 39,321,600 f32

  char* ws = (char*)d_ws;
  unsigned short* wq_  = (unsigned short*)ws;                   // q bf16  78.6MB
  unsigned short* wk_  = (unsigned short*)(ws + 78643200ULL);   // k bf16  78.6MB
  unsigned short* wctx = (unsigned short*)(ws + 157286400ULL);  // ctx bf16 78.6MB
  float* smax = (float*)(ws + 235929600ULL);                    // 614400 f32
  float* sinv = smax + 614400ULL;                               // 614400 f32

  dim3 blk(256);
  dim3 gp(600, 4);

  hipLaunchKernelGGL(HIP_KERNEL_NAME(gemm_k<0, 0>), gp, blk, 0, stream,
                     (const void*)query, Wq, bq, (void*)wq_);
  hipLaunchKernelGGL(HIP_KERNEL_NAME(gemm_k<0, 0>), gp, blk, 0, stream,
                     (const void*)key, Wk, bk, (void*)wk_);
  hipLaunchKernelGGL(HIP_KERNEL_NAME(gemm_k<0, 1>), gp, blk, 0, stream,
                     (const void*)value, Wv, bv, (void*)vhb);

  hipLaunchKernelGGL(scores_k, dim3(4, 4, 1536), blk, 0, stream, wq_, wk_, sc);
  hipLaunchKernelGGL(stats_k, dim3(153600), blk, 0, stream, sc, smax, sinv);
  hipLaunchKernelGGL(pv_k, dim3(7, 1536), blk, 0, stream, sc, vhb, smax, sinv, wctx);

  hipLaunchKernelGGL(HIP_KERNEL_NAME(gemm_k<1, 2>), gp, blk, 0, stream,
                     (const void*)wctx, Wo, bo, (void*)d_out);
}

// Round 2
// 1172.052 us; speedup vs baseline: 1.2073x; 1.2073x over previous
//
#include <hip/hip_runtime.h>

// ---------------------------------------------------------------------------
// AttentionLayer: B=16 S=12 N=400 D=512 H=8 HD=64
// outputs (flat, fp32): out[16,12,400,512] | scores_hb[128,12,400,400]
//                       | v_hb[128,12,400,64]
// ---------------------------------------------------------------------------

typedef float fvec4 __attribute__((ext_vector_type(4)));
typedef float f32x4 __attribute__((ext_vector_type(4)));
typedef unsigned short usvec4 __attribute__((ext_vector_type(4)));
typedef unsigned short usvec8 __attribute__((ext_vector_type(8)));
typedef short v8s __attribute__((ext_vector_type(8)));

#define DEV __device__ __forceinline__

DEV unsigned short f2bf(float f) {
  unsigned int u = __builtin_bit_cast(unsigned int, f);
  u += 0x7FFFu + ((u >> 16) & 1u);  // RNE
  return (unsigned short)(u >> 16);
}

DEV f32x4 mfma16(v8s a, v8s b, f32x4 c) {
  return __builtin_amdgcn_mfma_f32_16x16x32_bf16(a, b, c, 0, 0, 0);
}

DEV void gload16(const void* g, void* l) {
  __builtin_amdgcn_global_load_lds(
      (const __attribute__((address_space(1))) unsigned int*)g,
      (__attribute__((address_space(3))) unsigned int*)l, 16, 0, 0);
}

// ---------------------------------------------------------------------------
// fp32 -> bf16 convert (vectorized, grid-stride)
// ---------------------------------------------------------------------------
__global__ __launch_bounds__(256) void cvt_k(const float* __restrict__ in,
                                             unsigned short* __restrict__ o,
                                             long n) {
  const long stride = (long)gridDim.x * 256 * 8;
  for (long i = ((long)blockIdx.x * 256 + threadIdx.x) * 8; i < n; i += stride) {
    fvec4 a = *reinterpret_cast<const fvec4*>(in + i);
    fvec4 b = *reinterpret_cast<const fvec4*>(in + i + 4);
    usvec8 r;
    r[0] = f2bf(a[0]); r[1] = f2bf(a[1]); r[2] = f2bf(a[2]); r[3] = f2bf(a[3]);
    r[4] = f2bf(b[0]); r[5] = f2bf(b[1]); r[6] = f2bf(b[2]); r[7] = f2bf(b[3]);
    *reinterpret_cast<usvec8*>(o + i) = r;
  }
}

// all 4 weight matrices (512x512 each) in one launch; blockIdx.y selects
__global__ __launch_bounds__(256) void cvtw_k(const float* __restrict__ w0,
                                              const float* __restrict__ w1,
                                              const float* __restrict__ w2,
                                              const float* __restrict__ w3,
                                              unsigned short* __restrict__ o) {
  const float* w = (blockIdx.y == 0) ? w0 : (blockIdx.y == 1) ? w1
                 : (blockIdx.y == 2) ? w2 : w3;
  unsigned short* op = o + (long)blockIdx.y * 262144;
  long i = ((long)blockIdx.x * 256 + threadIdx.x) * 8;  // grid.x=128 -> exact
  fvec4 a = *reinterpret_cast<const fvec4*>(w + i);
  fvec4 b = *reinterpret_cast<const fvec4*>(w + i + 4);
  usvec8 r;
  r[0] = f2bf(a[0]); r[1] = f2bf(a[1]); r[2] = f2bf(a[2]); r[3] = f2bf(a[3]);
  r[4] = f2bf(b[0]); r[5] = f2bf(b[1]); r[6] = f2bf(b[2]); r[7] = f2bf(b[3]);
  *reinterpret_cast<usvec8*>(op + i) = r;
}

// ---------------------------------------------------------------------------
// bf16 GEMM: C[m][n] = sum_k A[m][k]*W[n][k] + bias[n];  M=76800 N=512 K=512
// 128x128x32 tile, 4 waves, global_load_lds width-16, m97 2-barrier loop.
// OMODE 0: bf16 -> o_h[m*512+n]
// OMODE 1: fp32 -> vhb scatter + bf16 -> wvt transposed [g][hd][node]
// OMODE 2: fp32 -> o_f[m*512+n]
// ---------------------------------------------------------------------------
template <int OMODE>
__global__ __launch_bounds__(256) void gemm_k(const unsigned short* __restrict__ A,
                                              const unsigned short* __restrict__ W,
                                              const float* __restrict__ bias,
                                              float* __restrict__ o_f,
                                              unsigned short* __restrict__ o_h,
                                              unsigned short* __restrict__ o_t) {
  __shared__ unsigned short sA[128 * 32];  // linear [128][32] bf16, 8 KB
  __shared__ unsigned short sB[128 * 32];
  const int t = threadIdx.x;
  const int lane = t & 63, wid = t >> 6;
  const int wm = wid >> 1, wn = wid & 1;
  const int lr = lane & 15, lg = lane >> 4;
  const long m0 = (long)blockIdx.x * 128;
  const int n0 = blockIdx.y * 128;

  // staging addresses: chunk c = wid + i*4 covers rows c*16..+15; LDS linear
  const int srow = wid * 16 + (lane >> 2);
  const int scol = (lane & 3) * 8;
  const unsigned short* aS0 = A + (m0 + srow) * 512 + scol;
  const unsigned short* aS1 = aS0 + 64 * 512;
  const unsigned short* bS0 = W + (long)(n0 + srow) * 512 + scol;
  const unsigned short* bS1 = bS0 + 64 * 512;
  unsigned short* lA0 = sA + wid * 512;
  unsigned short* lA1 = sA + (wid + 4) * 512;
  unsigned short* lB0 = sB + wid * 512;
  unsigned short* lB1 = sB + (wid + 4) * 512;

  f32x4 acc[4][4] = {};

  for (int k0 = 0; k0 < 512; k0 += 32) {
    __syncthreads();
    gload16(aS0 + k0, lA0);
    gload16(aS1 + k0, lA1);
    gload16(bS0 + k0, lB0);
    gload16(bS1 + k0, lB1);
    __syncthreads();

    v8s af[4], bf[4];
#pragma unroll
    for (int i = 0; i < 4; i++)
      af[i] = *reinterpret_cast<const v8s*>(&sA[(wm * 64 + i * 16 + lr) * 32 + lg * 8]);
#pragma unroll
    for (int j = 0; j < 4; j++)
      bf[j] = *reinterpret_cast<const v8s*>(&sB[(wn * 64 + j * 16 + lr) * 32 + lg * 8]);
#pragma unroll
    for (int i = 0; i < 4; i++)
#pragma unroll
      for (int j = 0; j < 4; j++) acc[i][j] = mfma16(af[i], bf[j], acc[i][j]);
  }

#pragma unroll
  for (int i = 0; i < 4; i++) {
#pragma unroll
    for (int j = 0; j < 4; j++) {
      const int gn = n0 + wn * 64 + j * 16 + lr;
      const float bv = bias[gn];
#pragma unroll
      for (int r = 0; r < 4; r++) {
        const long gm = m0 + wm * 64 + i * 16 + lg * 4 + r;
        const float val = acc[i][j][r] + bv;
        if (OMODE == 0) {
          o_h[gm * 512 + gn] = f2bf(val);
        } else if (OMODE == 1) {
          const int bs_lin = (int)(gm / 400);
          const int node = (int)(gm - (long)bs_lin * 400);
          const int h = gn >> 6, hd = gn & 63;
          o_f[(((long)(h * 192 + bs_lin) * 400 + node) << 6) + hd] = val;
          o_t[((long)(bs_lin * 8 + h) * 64 + hd) * 400 + node] = f2bf(val);
        } else {
          o_f[gm * 512 + gn] = val;
        }
      }
    }
  }
}

// ---------------------------------------------------------------------------
// Fused attention: per block = one (bs,h) group x 32 q-rows.
// 4 waves: wq = q-half (16 rows), wk = k-half (208 cols, 13 frags).
// S = QK^T/8 in registers -> write scores (f32) -> softmax stats via shfl+LDS
// -> P bf16 to LDS -> PV with V B-frags direct from global wvt (L2).
// ---------------------------------------------------------------------------
__global__ __launch_bounds__(256) void attn_k(
    const unsigned short* __restrict__ qm, const unsigned short* __restrict__ km,
    const unsigned short* __restrict__ vt, float* __restrict__ sc,
    unsigned short* __restrict__ ctx) {
  __shared__ unsigned short sP[32][424];  // pitch 848B: 16B-aligned, floor banks
  __shared__ float redM[2][32], redS[2][32];
  const int t = threadIdx.x;
  const int lane = t & 63, wid = t >> 6;
  const int wq = wid >> 1, wk = wid & 1;
  const int lr = lane & 15, lg = lane >> 4;
  const int g = blockIdx.y, bs = g >> 3, h = g & 7;
  const int q0 = blockIdx.x * 32;
  const long qkb = (long)bs * 204800 + h * 64;

  // Q A-frags (own rows, clamped)
  int qrow = q0 + wq * 16 + lr;
  if (qrow > 399) qrow = 399;
  const v8s aq0 = *reinterpret_cast<const v8s*>(qm + qkb + (long)qrow * 512 + lg * 8);
  const v8s aq1 = *reinterpret_cast<const v8s*>(qm + qkb + (long)qrow * 512 + 32 + lg * 8);

  f32x4 acc[13];
#pragma unroll
  for (int f = 0; f < 13; f++) acc[f] = f32x4{0.f, 0.f, 0.f, 0.f};

#pragma unroll
  for (int f = 0; f < 13; f++) {
    int kr = wk * 208 + f * 16 + lr;
    if (kr > 399) kr = 399;
    const v8s b0 = *reinterpret_cast<const v8s*>(km + qkb + (long)kr * 512 + lg * 8);
    const v8s b1 = *reinterpret_cast<const v8s*>(km + qkb + (long)kr * 512 + 32 + lg * 8);
    acc[f] = mfma16(aq0, b0, acc[f]);
    acc[f] = mfma16(aq1, b1, acc[f]);
  }

  // scale, write scores, per-lane row max
  const long sb = ((long)h * 192 + bs) * 160000;
  const int rowb = q0 + wq * 16 + lg * 4;  // + r
  const int rloc = wq * 16 + lg * 4;       // + r (block-local)
  float mx[4] = {-3.0e38f, -3.0e38f, -3.0e38f, -3.0e38f};
#pragma unroll
  for (int f = 0; f < 13; f++) {
    const int col = wk * 208 + f * 16 + lr;
#pragma unroll
    for (int r = 0; r < 4; r++) {
      float s = acc[f][r] * 0.125f;
      if (col >= 400) s = -3.0e38f;  // pad col
      acc[f][r] = s;
      mx[r] = fmaxf(mx[r], s);
      if (col < 400 && rowb + r < 400) sc[sb + (long)(rowb + r) * 400 + col] = s;
    }
  }
#pragma unroll
  for (int d = 1; d < 16; d <<= 1)
#pragma unroll
    for (int r = 0; r < 4; r++) mx[r] = fmaxf(mx[r], __shfl_xor(mx[r], d));
  if (lr == 0) {
#pragma unroll
    for (int r = 0; r < 4; r++) redM[wk][rloc + r] = mx[r];
  }
  __syncthreads();

  float M[4], sum[4] = {0.f, 0.f, 0.f, 0.f};
#pragma unroll
  for (int r = 0; r < 4; r++) M[r] = fmaxf(redM[0][rloc + r], redM[1][rloc + r]);
#pragma unroll
  for (int f = 0; f < 13; f++) {
#pragma unroll
    for (int r = 0; r < 4; r++) {
      float p = __expf(acc[f][r] - M[r]);  // pad cols -> exp(-inf)=0
      sum[r] += p;
      sP[rloc + r][wk * 208 + f * 16 + lr] = f2bf(p);
    }
  }
#pragma unroll
  for (int d = 1; d < 16; d <<= 1)
#pragma unroll
    for (int r = 0; r < 4; r++) sum[r] += __shfl_xor(sum[r], d);
  if (lr == 0) {
#pragma unroll
    for (int r = 0; r < 4; r++) redS[wk][rloc + r] = sum[r];
  }
  __syncthreads();

  float inv[4];
#pragma unroll
  for (int r = 0; r < 4; r++) inv[r] = 1.0f / (redS[0][rloc + r] + redS[1][rloc + r]);

  // PV: O[32 q][64 hd]; wave: wq q-half, wk hd-half (2 frags)
  const long vtb = (long)g * 25600;
  f32x4 o0 = {0.f, 0.f, 0.f, 0.f}, o1 = {0.f, 0.f, 0.f, 0.f};
#pragma unroll
  for (int ks = 0; ks < 13; ks++) {
    const v8s pa = *reinterpret_cast<const v8s*>(&sP[wq * 16 + lr][ks * 32 + lg * 8]);
    const v8s bv0 = *reinterpret_cast<const v8s*>(
        vt + vtb + (long)(wk * 32 + lr) * 400 + ks * 32 + lg * 8);
    const v8s bv1 = *reinterpret_cast<const v8s*>(
        vt + vtb + (long)(wk * 32 + 16 + lr) * 400 + ks * 32 + lg * 8);
    o0 = mfma16(pa, bv0, o0);
    o1 = mfma16(pa, bv1, o1);
  }

  const long cb = (long)bs * 400 * 512 + h * 64 + wk * 32;
#pragma unroll
  for (int r = 0; r < 4; r++) {
    const int row = rowb + r;
    if (row < 400) {
      ctx[cb + (long)row * 512 + lr] = f2bf(o0[r] * inv[r]);
      ctx[cb + (long)row * 512 + 16 + lr] = f2bf(o1[r] * inv[r]);
    }
  }
}

// ---------------------------------------------------------------------------

extern "C" void kernel_launch(void* const* d_in, const int* in_sizes, int n_in,
                              void* d_out, int out_size, void* d_ws, size_t ws_size,
                              hipStream_t stream) {
  (void)in_sizes; (void)n_in; (void)out_size; (void)ws_size;

  const float* query = (const float*)d_in[0];
  const float* key   = (const float*)d_in[1];
  const float* value = (const float*)d_in[2];
  const float* Wq = (const float*)d_in[3];
  const float* bq = (const float*)d_in[4];
  const float* Wk = (const float*)d_in[5];
  const float* bk = (const float*)d_in[6];
  const float* Wv = (const float*)d_in[7];
  const float* bv = (const float*)d_in[8];
  const float* Wo = (const float*)d_in[9];
  const float* bo = (const float*)d_in[10];

  float* out = (float*)d_out;       // 39,321,600 f32
  float* sc  = out + 39321600ULL;   // 245,760,000 f32 (scores)
  float* vhb = sc + 245760000ULL;   // 39,321,600 f32

  // cvt scratch lives in the scores region (dead until attn_k runs)
  unsigned short* scbuf = (unsigned short*)sc;

  // ws: wq_(=wctx alias) | wk_ | wvt | wW4   -> ~238 MB
  char* ws = (char*)d_ws;
  unsigned short* wq_  = (unsigned short*)ws;                   // 78.6 MB
  unsigned short* wk_  = (unsigned short*)(ws + 78643200ULL);   // 78.6 MB
  unsigned short* wvt  = (unsigned short*)(ws + 157286400ULL);  // 78.6 MB
  unsigned short* wW   = (unsigned short*)(ws + 235929600ULL);  // 2 MB
  unsigned short* wctx = wq_;  // safe alias: each attn block reads exactly the
                               // Q rectangle it later overwrites, with two
                               // __syncthreads in between.

  const long NEL = 39321600;
  dim3 blk(256);
  dim3 gp(600, 4);

  hipLaunchKernelGGL(cvtw_k, dim3(128, 4), blk, 0, stream, Wq, Wk, Wv, Wo, wW);

  hipLaunchKernelGGL(cvt_k, dim3(2400), blk, 0, stream, query, scbuf, NEL);
  hipLaunchKernelGGL(HIP_KERNEL_NAME(gemm_k<0>), gp, blk, 0, stream,
                     scbuf, wW, bq, (float*)nullptr, wq_, (unsigned short*)nullptr);

  hipLaunchKernelGGL(cvt_k, dim3(2400), blk, 0, stream, key, scbuf, NEL);
  hipLaunchKernelGGL(HIP_KERNEL_NAME(gemm_k<0>), gp, blk, 0, stream,
                     scbuf, wW + 262144, bk, (float*)nullptr, wk_, (unsigned short*)nullptr);

  hipLaunchKernelGGL(cvt_k, dim3(2400), blk, 0, stream, value, scbuf, NEL);
  hipLaunchKernelGGL(HIP_KERNEL_NAME(gemm_k<1>), gp, blk, 0, stream,
                     scbuf, wW + 524288, bv, vhb, (unsigned short*)nullptr, wvt);

  hipLaunchKernelGGL(attn_k, dim3(13, 1536), blk, 0, stream, wq_, wk_, wvt, sc, wctx);

  hipLaunchKernelGGL(HIP_KERNEL_NAME(gemm_k<2>), gp, blk, 0, stream,
                     wctx, wW + 786432, bo, out, (unsigned short*)nullptr,
                     (unsigned short*)nullptr);
}